// Round 11
// baseline (206.114 us; speedup 1.0000x reference)
//
#include <hip/hip_runtime.h>

#define DIM 1024
#define HEADS 16
#define BB 2
#define NN 2048
#define HD 64
#define M_ROWS (BB*NN)  // 4096

typedef __bf16 bf16x8 __attribute__((ext_vector_type(8)));
typedef float f32x4 __attribute__((ext_vector_type(4)));
typedef short s16x4 __attribute__((ext_vector_type(4)));

__device__ inline unsigned short f2bf(float f) {
    unsigned int u = __builtin_bit_cast(unsigned int, f);
    u += 0x7fffu + ((u >> 16) & 1u);
    return (unsigned short)(u >> 16);
}
__device__ inline float bf2f(unsigned short u) {
    return __builtin_bit_cast(float, (unsigned int)u << 16);
}
__device__ inline bf16x8 as_bf16x8(uint4 v) {
    return __builtin_bit_cast(bf16x8, v);
}
// async global->LDS, 16B per lane: LDS dest = base + lane*16 (wave-uniform
// base); global source address is per-lane (gather allowed).
__device__ __forceinline__ void gl_lds16(const unsigned short* g, unsigned short* l) {
    __builtin_amdgcn_global_load_lds(
        (const __attribute__((address_space(1))) unsigned int*)g,
        (__attribute__((address_space(3))) unsigned int*)l, 16, 0, 0);
}

// 16x16x16 bf16 MFMA (K=16): A/B = 4 bf16 (2 VGPRs), C/D = 4 f32.
__device__ __forceinline__ f32x4 mfma16x16x16bf16(s16x4 a, s16x4 b, f32x4 c) {
#if __has_builtin(__builtin_amdgcn_mfma_f32_16x16x16bf16_1k)
    return __builtin_amdgcn_mfma_f32_16x16x16bf16_1k(a, b, c, 0, 0, 0);
#else
    asm volatile("v_mfma_f32_16x16x16_bf16 %0, %1, %2, %0"
                 : "+v"(c) : "v"(a), "v"(b));
    return c;
#endif
}

// ---------------------------------------------------------------------------
// Merged prep: blocks 0..1023 = weight transpose in 64x64 f32 tiles;
// blocks 1024..3071 = activation bf16 prep.
// ---------------------------------------------------------------------------
__global__ __launch_bounds__(256) void prep_all(
    const float* __restrict__ y2f, const float* __restrict__ y2b,
    const float* __restrict__ Wq, const float* __restrict__ Wk,
    const float* __restrict__ Wv, const float* __restrict__ Wo,
    unsigned short* __restrict__ Af, unsigned short* __restrict__ Ab,
    unsigned short* __restrict__ As, unsigned short* __restrict__ Wt_all)
{
    __shared__ float tile[64][68];    // 17.4 KB; rows 272B (16B-aligned)
    const int blk = blockIdx.x;
    if (blk < 1024) {
        const int m = blk >> 8, r = blk & 255, bk = r & 15, bn = r >> 4;
        const float* W = (m == 0) ? Wq : (m == 1) ? Wk : (m == 2) ? Wv : Wo;
        const int tx = threadIdx.x & 15, ty = threadIdx.x >> 4;  // 16 x 16
        #pragma unroll
        for (int i = 0; i < 64; i += 16)
            *(float4*)(&tile[ty + i][tx*4]) =
                *(const float4*)(&W[(size_t)(bk*64 + ty + i)*DIM + bn*64 + tx*4]);
        __syncthreads();
        unsigned short* dst = Wt_all + (size_t)m * DIM * DIM;
        #pragma unroll
        for (int i = 0; i < 2; i++) {
            int chunk = i*256 + threadIdx.x;        // 0..511
            int n = chunk >> 3, kc = (chunk & 7)*8; // Wt row = n, col kc..kc+7
            unsigned int p0 = (unsigned)f2bf(tile[kc+0][n]) | ((unsigned)f2bf(tile[kc+1][n]) << 16);
            unsigned int p1 = (unsigned)f2bf(tile[kc+2][n]) | ((unsigned)f2bf(tile[kc+3][n]) << 16);
            unsigned int p2 = (unsigned)f2bf(tile[kc+4][n]) | ((unsigned)f2bf(tile[kc+5][n]) << 16);
            unsigned int p3 = (unsigned)f2bf(tile[kc+6][n]) | ((unsigned)f2bf(tile[kc+7][n]) << 16);
            *(uint4*)(&dst[(size_t)(bn*64 + n)*DIM + bk*64 + kc]) = uint4{p0, p1, p2, p3};
        }
    } else {
        const size_t idx = ((size_t)(blk - 1024)*256 + threadIdx.x) * 8;
        #pragma unroll
        for (int half = 0; half < 2; half++) {
            float4 f = *(const float4*)(y2f + idx + half*4);
            float4 b = *(const float4*)(y2b + idx + half*4);
            ushort4 of, ob, os;
            of.x = f2bf(f.x); of.y = f2bf(f.y); of.z = f2bf(f.z); of.w = f2bf(f.w);
            ob.x = f2bf(b.x); ob.y = f2bf(b.y); ob.z = f2bf(b.z); ob.w = f2bf(b.w);
            os.x = f2bf(f.x + b.x); os.y = f2bf(f.y + b.y);
            os.z = f2bf(f.z + b.z); os.w = f2bf(f.w + b.w);
            *(ushort4*)(Af + idx + half*4) = of;
            *(ushort4*)(Ab + idx + half*4) = ob;
            *(ushort4*)(As + idx + half*4) = os;
        }
    }
}

// ---------------------------------------------------------------------------
// Uniform QKV GEMM: 8 waves, 128x128 tile, T4 counted vmcnt(2) 3-buffer
// pipeline, bm-major intra-XCD swizzle (A-panel L2 reuse), T2 LDS swizzle.
// ---------------------------------------------------------------------------
__global__ __launch_bounds__(512) void gemm_qkv(
    const unsigned short* __restrict__ Af, const unsigned short* __restrict__ Ab,
    const unsigned short* __restrict__ As,
    const unsigned short* __restrict__ Wt_all,
    const float* __restrict__ bq, const float* __restrict__ bk,
    const float* __restrict__ bv,
    unsigned short* __restrict__ Qh, unsigned short* __restrict__ Kh,
    unsigned short* __restrict__ Vt)
{
    const int lin = blockIdx.x + 32*blockIdx.y;
    const int xcd = lin & 7, j = lin >> 3;  // XCD id, intra-XCD index 0..95
    const int bm = j / 3;                   // bm-major: A panel shared across
    const int rest = 3*xcd + (j % 3);       //  the 3 in-flight combos
    const int mode = rest >> 3;             // 0=Q, 1=K, 2=V
    const int bn = rest & 7;
    __shared__ __align__(16) unsigned short smem[3*8192];   // 48 KB
    const int t = threadIdx.x;
    const int w = t >> 6, lane = t & 63, ln = lane & 15, quad = lane >> 4;
    const int wm = w >> 1, wn = w & 1;      // 4 x 2 wave grid (32r x 64c each)
    const unsigned short* Wt = Wt_all + (size_t)mode * (DIM*DIM);
    const unsigned short* A0 = (mode == 0) ? Af : (mode == 1) ? Ab : As;

    const int srow = lane >> 2;             // 16 rows per wave-load
    // source col pre-swizzle: LDS pos (row, c) holds element c ^ ((row>>1)&3)
    const int scol = (((lane & 3) ^ ((lane >> 3) & 3)) * 8);

    const unsigned short* gA0 = A0 + (size_t)(bm*128 + w*16 + srow)*DIM + scol;
    const unsigned short* gB0 = Wt + (size_t)(bn*128 + w*16 + srow)*DIM + scol;

    // fragment read: element quad lives at col8 = quad ^ ((ln>>1)&3)
    const int cswz = (quad ^ ((ln >> 1) & 3)) * 8;
    const int aoff = (wm*32 + ln)*32 + cswz;            // + mi*512
    const int boff = 4096 + (wn*64 + ln)*32 + cswz;     // + ni*512

    f32x4 acc[2][4];
    #pragma unroll
    for (int mi = 0; mi < 2; mi++)
        #pragma unroll
        for (int ni = 0; ni < 4; ni++)
            acc[mi][ni] = (f32x4){0.f, 0.f, 0.f, 0.f};

#define STAGE_Q(BUF) do { \
        unsigned short* s_ = smem + (BUF)*8192; \
        gl_lds16(gA0, &s_[(w*16)*32]); \
        gl_lds16(gB0, &s_[4096 + (w*16)*32]); \
        gA0 += 32; gB0 += 32; } while (0)

#define COMP_Q(BUF) do { \
        const unsigned short* s_ = smem + (BUF)*8192; \
        bf16x8 af[2], bfr[4]; \
        _Pragma("unroll") \
        for (int mi = 0; mi < 2; mi++) \
            af[mi] = as_bf16x8(*(const uint4*)(s_ + aoff + mi*512)); \
        _Pragma("unroll") \
        for (int ni = 0; ni < 4; ni++) \
            bfr[ni] = as_bf16x8(*(const uint4*)(s_ + boff + ni*512)); \
        _Pragma("unroll") \
        for (int mi = 0; mi < 2; mi++) \
            _Pragma("unroll") \
            for (int ni = 0; ni < 4; ni++) \
                acc[mi][ni] = __builtin_amdgcn_mfma_f32_16x16x32_bf16(af[mi], bfr[ni], acc[mi][ni], 0, 0, 0); \
    } while (0)

#define QITER(B) do { \
        asm volatile("s_waitcnt vmcnt(2)" ::: "memory"); \
        __builtin_amdgcn_s_barrier(); \
        __builtin_amdgcn_sched_barrier(0); \
        STAGE_Q(((B) + 2) % 3); \
        COMP_Q(B); \
        __builtin_amdgcn_sched_barrier(0); \
    } while (0)

    STAGE_Q(0);
    STAGE_Q(1);
    for (int base = 0; base < 30; base += 3) {
        QITER(0); QITER(1); QITER(2);
    }
    asm volatile("s_waitcnt vmcnt(2)" ::: "memory");
    __builtin_amdgcn_s_barrier();
    __builtin_amdgcn_sched_barrier(0);
    COMP_Q(0);
    __builtin_amdgcn_sched_barrier(0);
    asm volatile("s_waitcnt vmcnt(0)" ::: "memory");
    __builtin_amdgcn_s_barrier();
    __builtin_amdgcn_sched_barrier(0);
    COMP_Q(1);
#undef QITER
#undef COMP_Q
#undef STAGE_Q

    const float* bias = (mode == 0) ? bq : (mode == 1) ? bk : bv;
    unsigned short* dst = (mode == 0) ? Qh : (mode == 1) ? Kh : Vt;
    if (mode < 2) {
        const float sc = (mode == 0) ? 0.125f * 1.4426950408889634f : 1.0f;
        #pragma unroll
        for (int mi = 0; mi < 2; mi++) {
            #pragma unroll
            for (int r = 0; r < 4; r++) {
                int grow = bm*128 + wm*32 + mi*16 + quad*4 + r;
                int b_ = grow >> 11, n = grow & (NN - 1);
                #pragma unroll
                for (int ni = 0; ni < 4; ni++) {
                    int gcol = bn*128 + wn*64 + ni*16 + ln;
                    int hh = gcol >> 6, dd = gcol & 63;
                    float val = (acc[mi][ni][r] + bias[gcol]) * sc;
                    dst[(((size_t)(b_*HEADS + hh))*NN + n)*HD + dd] = f2bf(val);
                }
            }
        }
    } else {
        // V: single-pass transpose through swizzled sT[128 dd][128 nn]
        __syncthreads();
        #pragma unroll
        for (int ni = 0; ni < 4; ni++) {
            int row_s = wn*64 + ni*16 + ln;            // local feature col dd
            float bsv = bias[bn*128 + row_s];
            int sxor = (row_s & 7) << 1;               // 8B-unit XOR swizzle
            #pragma unroll
            for (int mi = 0; mi < 2; mi++) {
                int u = wm*8 + mi*4 + quad;            // 8B unit along nn (0..31)
                ushort4 pk;
                pk.x = f2bf(acc[mi][ni][0] + bsv);
                pk.y = f2bf(acc[mi][ni][1] + bsv);
                pk.z = f2bf(acc[mi][ni][2] + bsv);
                pk.w = f2bf(acc[mi][ni][3] + bsv);
                *(ushort4*)(&smem[row_s*128 + ((u ^ sxor) << 2)]) = pk;
            }
        }
        __syncthreads();
        const int b_ = bm >> 4;
        #pragma unroll
        for (int i = 0; i < 4; i++) {
            int idx = i*512 + t;                        // 0..2047 16B chunks
            int dd = idx >> 4, jc = idx & 15;
            int u = (jc*2) ^ ((dd & 7) << 1);
            int hh = bn*2 + (dd >> 6), d_ = dd & 63;
            *(uint4*)(dst + (((size_t)(b_*HEADS + hh))*HD + d_)*NN
                          + (size_t)(bm & 15)*128 + jc*8)
                = *(const uint4*)(&smem[dd*128 + (u << 2)]);
        }
    }
}

// ---------------------------------------------------------------------------
// Out projection: 8-wave 128x128 tile, 4-buffer depth-3 pipeline vmcnt(4)
// (1 block/CU -> latency hiding from pipeline depth), XCD-pinned Wo panel,
// T2 LDS swizzle. f32 epilogue.
// ---------------------------------------------------------------------------
__global__ __launch_bounds__(512) void gemm_out(
    const unsigned short* __restrict__ attp,
    const unsigned short* __restrict__ Wt_all,
    const float* __restrict__ bo, float* __restrict__ out)
{
    const int lin = blockIdx.x + 32*blockIdx.y;   // 0..255
    const int bn = lin & 7;                       // XCD id == Wo panel
    const int bm = lin >> 3;                      // 0..31
    __shared__ __align__(16) unsigned short smem[4*8192];   // 64 KB
    const int t = threadIdx.x;
    const int w = t >> 6, lane = t & 63, ln = lane & 15, quad = lane >> 4;
    const int wm = w >> 1, wn = w & 1;
    const unsigned short* Wt = Wt_all + (size_t)3 * (DIM*DIM);

    const int srow = lane >> 2;
    const int scol = (((lane & 3) ^ ((lane >> 3) & 3)) * 8);

    const unsigned short* gA0 = attp + (size_t)(bm*128 + w*16 + srow)*DIM + scol;
    const unsigned short* gB0 = Wt + (size_t)(bn*128 + w*16 + srow)*DIM + scol;

    const int cswz = (quad ^ ((ln >> 1) & 3)) * 8;
    const int aoff = (wm*32 + ln)*32 + cswz;            // + mi*512
    const int boff = 4096 + (wn*64 + ln)*32 + cswz;     // + ni*512

    f32x4 acc[2][4];
    #pragma unroll
    for (int mi = 0; mi < 2; mi++)
        #pragma unroll
        for (int ni = 0; ni < 4; ni++)
            acc[mi][ni] = (f32x4){0.f, 0.f, 0.f, 0.f};

#define STAGE_T(BUF) do { \
        unsigned short* s_ = smem + (BUF)*8192; \
        gl_lds16(gA0, &s_[(w*16)*32]); \
        gl_lds16(gB0, &s_[4096 + (w*16)*32]); \
        gA0 += 32; gB0 += 32; } while (0)

#define COMP_T(BUF) do { \
        const unsigned short* s_ = smem + (BUF)*8192; \
        bf16x8 af[2], bfr[4]; \
        _Pragma("unroll") \
        for (int mi = 0; mi < 2; mi++) \
            af[mi] = as_bf16x8(*(const uint4*)(s_ + aoff + mi*512)); \
        _Pragma("unroll") \
        for (int ni = 0; ni < 4; ni++) \
            bfr[ni] = as_bf16x8(*(const uint4*)(s_ + boff + ni*512)); \
        _Pragma("unroll") \
        for (int mi = 0; mi < 2; mi++) \
            _Pragma("unroll") \
            for (int ni = 0; ni < 4; ni++) \
                acc[mi][ni] = __builtin_amdgcn_mfma_f32_16x16x32_bf16(af[mi], bfr[ni], acc[mi][ni], 0, 0, 0); \
    } while (0)

// region k: tiles k,k+1,k+2 in flight (6 loads); vmcnt(4) -> tile k landed.
// stage tile k+3 into buf (k+3)%4 = (k-1)%4 (freed by last region's barrier).
#define TITER(B, S) do { \
        asm volatile("s_waitcnt vmcnt(4)" ::: "memory"); \
        __builtin_amdgcn_s_barrier(); \
        __builtin_amdgcn_sched_barrier(0); \
        STAGE_T(S); \
        COMP_T(B); \
        __builtin_amdgcn_sched_barrier(0); \
    } while (0)

    STAGE_T(0);
    STAGE_T(1);
    STAGE_T(2);
    for (int g = 0; g < 7; ++g) {           // regions 0..27 (tiles 0..27)
        TITER(0, 3); TITER(1, 0); TITER(2, 1); TITER(3, 2);
    }
    TITER(0, 3);                            // region 28 (stage tile 31)
    asm volatile("s_waitcnt vmcnt(4)" ::: "memory");   // tile 29 landed
    __builtin_amdgcn_s_barrier();
    __builtin_amdgcn_sched_barrier(0);
    COMP_T(1);
    __builtin_amdgcn_sched_barrier(0);
    asm volatile("s_waitcnt vmcnt(2)" ::: "memory");   // tile 30 landed
    __builtin_amdgcn_s_barrier();
    __builtin_amdgcn_sched_barrier(0);
    COMP_T(2);
    __builtin_amdgcn_sched_barrier(0);
    asm volatile("s_waitcnt vmcnt(0)" ::: "memory");   // tile 31 landed
    __builtin_amdgcn_s_barrier();
    __builtin_amdgcn_sched_barrier(0);
    COMP_T(3);
#undef TITER
#undef COMP_T
#undef STAGE_T

    #pragma unroll
    for (int mi = 0; mi < 2; mi++) {
        #pragma unroll
        for (int r = 0; r < 4; r++) {
            int grow = bm*128 + wm*32 + mi*16 + quad*4 + r;
            #pragma unroll
            for (int ni = 0; ni < 4; ni++) {
                int gcol = bn*128 + wn*64 + ni*16 + ln;
                out[(size_t)grow*DIM + gcol] = acc[mi][ni][r] + bo[gcol];
            }
        }
    }
}

// ---------------------------------------------------------------------------
// Flash attention (best-known R6/R9 form; frozen — bench-insensitive to
// attn variants across R3-R9, profiled number carries ±8us session noise).
// ---------------------------------------------------------------------------
__global__ __launch_bounds__(256) void attn_kernel(
    const unsigned short* __restrict__ Qh, const unsigned short* __restrict__ Kh,
    const unsigned short* __restrict__ Vt, const unsigned short* __restrict__ As,
    unsigned short* __restrict__ attp)
{
    const int bh = blockIdx.x;      // b*16 + h
    const int qt = blockIdx.y;      // 0..15 (128-row q tiles)
    const int b = bh >> 4, h = bh & 15;
    const int t = threadIdx.x;
    const int w = t >> 6, lane = t & 63, ln = lane & 15, quad = lane >> 4;
    const int sw = ln & 7;          // fragment rows are == ln (mod 8)
    const float EBIAS = 17.312340490667562f;   // 12 * log2(e)

    __shared__ __align__(16) unsigned short sK[2][64*64];    // 16 KB [n][k]
    __shared__ __align__(16) unsigned short sVt[2][64*64];   // 16 KB [d][n]

    const unsigned short* Qb  = Qh + (size_t)bh * NN * HD + (size_t)qt * 128 * HD;
    const unsigned short* Kb  = Kh + (size_t)bh * NN * HD;
    const unsigned short* Vtb = Vt + (size_t)bh * HD * NN;   // [d][n]

    const int rl = lane >> 3, cb = lane & 7;

    // ---- Q fragments straight from global: 2 m-tiles x 2 k-frags ----
    bf16x8 aq[2][2];
    #pragma unroll
    for (int m = 0; m < 2; m++)
        #pragma unroll
        for (int k = 0; k < 2; k++)
            aq[m][k] = as_bf16x8(*(const uint4*)(
                Qb + (size_t)(m*64 + w*16 + ln)*HD + (k*4 + quad)*8));

    // stage tile jt into buffer bb (4 gl_lds16 per wave; XOR-swizzled cols)
#define STAGE_KV(JT, BBUF) do { \
        _Pragma("unroll") \
        for (int j = 0; j < 2; j++) { \
            int row = w*16 + j*8 + rl; \
            gl_lds16(Kb + (size_t)((JT)*64 + row)*HD + ((cb ^ (row & 7))*8), \
                     &sK[BBUF][(w*16 + j*8)*64]); \
            gl_lds16(Vtb + (size_t)row*NN + (JT)*64 + ((cb ^ (row & 7))*8), \
                     &sVt[BBUF][(w*16 + j*8)*64]); \
        } } while (0)

    const s16x4 ones = { (short)0x3F80, (short)0x3F80, (short)0x3F80, (short)0x3F80 };
    const f32x4 CB = (f32x4){-EBIAS, -EBIAS, -EBIAS, -EBIAS};  // persistent C-init
    f32x4 accO[2][4], accL[2];
    #pragma unroll
    for (int m = 0; m < 2; m++) {
        accL[m] = (f32x4){0.f, 0.f, 0.f, 0.f};
        #pragma unroll
        for (int di = 0; di < 4; di++) accO[m][di] = (f32x4){0.f, 0.f, 0.f, 0.f};
    }

    STAGE_KV(0, 0);                       // prologue: tile 0 -> buf 0
    asm volatile("s_waitcnt vmcnt(0)" ::: "memory");
    __builtin_amdgcn_s_barrier();
    __builtin_amdgcn_sched_barrier(0);

    #pragma unroll 2
    for (int jt = 0; jt < 32; jt++) {
        const int cur = jt & 1;
        if (jt < 31) STAGE_KV(jt + 1, cur ^ 1);   // issue next tile first

        const unsigned short* sKc = sK[cur];
        const unsigned short* sVc = sVt[cur];

        // S^T: accS[m][ni] — lane: q-col = m*64+w*16+ln, kv = ni*16+quad*4+r.
        // First MFMA of each chain takes CB (-EBIAS) as C: no init movs.
        f32x4 accS[2][4];
        __builtin_amdgcn_s_setprio(1);
        #pragma unroll
        for (int ni = 0; ni < 4; ni++) {
            bf16x8 b0 = as_bf16x8(*(const uint4*)(
                &sKc[(ni*16 + ln)*64 + (((0 + quad) ^ sw)*8)]));
            accS[0][ni] = __builtin_amdgcn_mfma_f32_16x16x32_bf16(b0, aq[0][0], CB, 0, 0, 0);
            accS[1][ni] = __builtin_amdgcn_mfma_f32_16x16x32_bf16(b0, aq[1][0], CB, 0, 0, 0);
            bf16x8 b1 = as_bf16x8(*(const uint4*)(
                &sKc[(ni*16 + ln)*64 + (((4 + quad) ^ sw)*8)]));
            accS[0][ni] = __builtin_amdgcn_mfma_f32_16x16x32_bf16(b1, aq[0][1], accS[0][ni], 0, 0, 0);
            accS[1][ni] = __builtin_amdgcn_mfma_f32_16x16x32_bf16(b1, aq[1][1], accS[1][ni], 0, 0, 0);
        }
        __builtin_amdgcn_s_setprio(0);

        // p = exp2(s-EBIAS); pack via v_perm (trunc); L via ones-MFMA
        s16x4 pf[2][4];
        #pragma unroll
        for (int m = 0; m < 2; m++)
            #pragma unroll
            for (int ni = 0; ni < 4; ni++) {
                unsigned int e0 = __builtin_bit_cast(unsigned int, __builtin_amdgcn_exp2f(accS[m][ni][0]));
                unsigned int e1 = __builtin_bit_cast(unsigned int, __builtin_amdgcn_exp2f(accS[m][ni][1]));
                unsigned int e2 = __builtin_bit_cast(unsigned int, __builtin_amdgcn_exp2f(accS[m][ni][2]));
                unsigned int e3 = __builtin_bit_cast(unsigned int, __builtin_amdgcn_exp2f(accS[m][ni][3]));
                unsigned int lo = __builtin_amdgcn_perm(e1, e0, 0x07060302u);
                unsigned int hi = __builtin_amdgcn_perm(e3, e2, 0x07060302u);
                pf[m][ni] = __builtin_bit_cast(s16x4, uint2{lo, hi});
                accL[m] = mfma16x16x16bf16(pf[m][ni], ones, accL[m]);
            }

        // O += P V: one V-frag read feeds both m-tiles.
        __builtin_amdgcn_s_setprio(1);
        #pragma unroll
        for (int ni = 0; ni < 4; ni++) {
            int blkv = 2*ni + (quad >> 1);
            int off = (quad & 1) * 4;
            #pragma unroll
            for (int di = 0; di < 4; di++) {
                s16x4 bv = __builtin_bit_cast(s16x4,
                    *(const uint2*)(&sVc[(di*16 + ln)*64 + ((blkv ^ sw)*8) + off]));
                accO[0][di] = mfma16x16x16bf16(pf[0][ni], bv, accO[0][di]);
                accO[1][di] = mfma16x16x16bf16(pf[1][ni], bv, accO[1][di]);
            }
        }
        __builtin_amdgcn_s_setprio(0);

        __builtin_amdgcn_sched_barrier(0);
        if (jt < 31) {
            asm volatile("s_waitcnt vmcnt(0)" ::: "memory");  // next tile landed
            __builtin_amdgcn_s_barrier();                     // cur fully read
            __builtin_amdgcn_sched_barrier(0);
        }
    }
#undef STAGE_KV

    // accL[m][r] = row-sum L for q-row m*64 + w*16 + quad*4 + r
    #pragma unroll
    for (int m = 0; m < 2; m++) {
        #pragma unroll
        for (int r = 0; r < 4; r++) {
            float inv = 1.f / accL[m][r];
            int n = qt*128 + m*64 + w*16 + quad*4 + r;
            #pragma unroll
            for (int di = 0; di < 4; di++) {
                int c = h*64 + di*16 + ln;
                size_t gi = ((size_t)b*NN + n)*DIM + c;
                float o = accO[m][di][r]*inv + bf2f(As[gi]);
                attp[gi] = f2bf(o);
            }
        }
    }
}

// ---------------------------------------------------------------------------
extern "C" void kernel_launch(void* const* d_in, const int* in_sizes, int n_in,
                              void* d_out, int out_size, void* d_ws, size_t ws_size,
                              hipStream_t stream) {
    const float* y2f = (const float*)d_in[0];
    const float* y2b = (const float*)d_in[1];
    const float* Wq  = (const float*)d_in[2];
    const float* bq  = (const float*)d_in[3];
    const float* Wk  = (const float*)d_in[4];
    const float* bk  = (const float*)d_in[5];
    const float* Wv  = (const float*)d_in[6];
    const float* bv  = (const float*)d_in[7];
    const float* Wo  = (const float*)d_in[8];
    const float* bo  = (const float*)d_in[9];
    float* out = (float*)d_out;

    const size_t NACT = (size_t)M_ROWS * DIM;  // 4,194,304 (8 MB as ushort)
    unsigned short* ws   = (unsigned short*)d_ws;
    unsigned short* Af   = ws;
    unsigned short* Ab   = ws + NACT;
    unsigned short* As   = ws + 2*NACT;
    unsigned short* Qh   = ws + 3*NACT;
    unsigned short* Kh   = ws + 4*NACT;
    unsigned short* Vt   = ws + 5*NACT;   // V written pre-transposed [b,h,d,n]
    unsigned short* Wt   = ws + 6*NACT;   // 4 x 1024 x 1024 bf16
    unsigned short* attp = Ab;            // overlay (Ab dead after QKV gemm)

    prep_all<<<dim3(3072), 256, 0, stream>>>(y2f, y2b, Wq, Wk, Wv, Wo,
                                             Af, Ab, As, Wt);
    gemm_qkv<<<dim3(32, 24), 512, 0, stream>>>(
        Af, Ab, As, Wt, bq, bk, bv, Qh, Kh, Vt);
    attn_kernel<<<dim3(32, 16), 256, 0, stream>>>(Qh, Kh, Vt, As, attp);
    gemm_out<<<dim3(32, 8), 512, 0, stream>>>(attp, Wt, bo, out);
}